// Round 9
// baseline (326.715 us; speedup 1.0000x reference)
//
#include <hip/hip_runtime.h>
#include <math.h>

#define ND 64
#define ED 32
#define GD 32
#define HD 128
#define DOF 6
#define K1 172      // 2*ND + ED + 12
#define K1PAD 192   // padded to 6 chunks of 32
#define KG 224      // HD + ND + GD (7 chunks of 32)
#define N4P 80      // W4 cols padded 70 -> 80 (5 n-tiles)
#define NOUT 70
#define OUTC 77
#define MT 256      // directions per edge block (4 waves x 64)
#define P1 132      // edge h1 LDS pitch (bf16): 264B rows; b64 access pattern measured 0-conflict (r6)
#define NACCP 132   // node accumulator pitch (fp32)
#define NACC_CAP 124
#define TDN 16      // nodes per node block
#define GP 232      // node gbuf pitch (bf16)
#define HP 136      // node hidden pitch (bf16)
#define OP 84       // node obuf pitch (fp32)
#define SCB 2048    // scan block chunk
#define PI_F 3.14159265358979f

typedef short short8 __attribute__((ext_vector_type(8)));
typedef float f32x4  __attribute__((ext_vector_type(4)));

__device__ __forceinline__ unsigned short f2b(float f) {
    unsigned int u = __float_as_uint(f);
    u += 0x7fffu + ((u >> 16) & 1u);
    return (unsigned short)(u >> 16);
}
__device__ __forceinline__ float b2f(unsigned short b) {
    return __uint_as_float(((unsigned int)b) << 16);
}
__device__ __forceinline__ void mul33_abt(const float* A, const float* B, float* C) {
#pragma unroll
    for (int r = 0; r < 3; r++)
#pragma unroll
        for (int c = 0; c < 3; c++)
            C[3*r+c] = A[3*r+0]*B[3*c+0] + A[3*r+1]*B[3*c+1] + A[3*r+2]*B[3*c+2];
}

// Pack weights to MFMA fragment layout + bf16-convert xfeat/edge_feat + degree count.
// frag: off(k,n) = (((kc*NT + nt)*4 + quad)*16 + nl)*8 + j. W3 PLAIN (sums are plain-column now).
__global__ void __launch_bounds__(256)
prep(const float* __restrict__ W1, const float* __restrict__ W2,
     const float* __restrict__ W3, const float* __restrict__ W4,
     const float* __restrict__ xfeat, const float* __restrict__ edge_feat,
     const int* __restrict__ edge_index,
     unsigned short* __restrict__ W1b, unsigned short* __restrict__ W2b,
     unsigned short* __restrict__ W3b, unsigned short* __restrict__ W4b,
     unsigned short* __restrict__ xb, unsigned short* __restrict__ eb,
     int* __restrict__ cnti, int N, int E)
{
    int idx = blockIdx.x * 256 + threadIdx.x;
    if (idx < K1PAD * HD) {
        int k = idx >> 7, n = idx & 127;
        float v = (k < K1) ? W1[k * HD + n] : 0.f;
        int kc = k >> 5, kr = k & 31, q = kr >> 3, j = kr & 7;
        W1b[(((kc * 8 + (n >> 4)) * 4 + q) * 16 + (n & 15)) * 8 + j] = f2b(v);
        return;
    }
    idx -= K1PAD * HD;
    if (idx < HD * HD) {
        int k = idx >> 7, n = idx & 127;
        int kc = k >> 5, kr = k & 31, q = kr >> 3, j = kr & 7;
        W2b[(((kc * 8 + (n >> 4)) * 4 + q) * 16 + (n & 15)) * 8 + j] = f2b(W2[k * HD + n]);
        return;
    }
    idx -= HD * HD;
    if (idx < KG * HD) {
        int k = idx >> 7, n = idx & 127;
        int kc = k >> 5, kr = k & 31, q = kr >> 3, j = kr & 7;
        W3b[(((kc * 8 + (n >> 4)) * 4 + q) * 16 + (n & 15)) * 8 + j] = f2b(W3[k * HD + n]);
        return;
    }
    idx -= KG * HD;
    if (idx < HD * N4P) {
        int k = idx / N4P, n = idx % N4P;
        float v = (n < NOUT) ? W4[k * NOUT + n] : 0.f;
        int kc = k >> 5, kr = k & 31, q = kr >> 3, j = kr & 7;
        W4b[(((kc * 5 + (n >> 4)) * 4 + q) * 16 + (n & 15)) * 8 + j] = f2b(v);
        return;
    }
    idx -= HD * N4P;
    const int nx4 = N * ND / 4;
    if (idx < nx4) {
        const float4 v = *(const float4*)&xfeat[idx * 4];
        ushort4 o; o.x = f2b(v.x); o.y = f2b(v.y); o.z = f2b(v.z); o.w = f2b(v.w);
        *(ushort4*)&xb[idx * 4] = o;
        return;
    }
    idx -= nx4;
    const int ne4 = E * ED / 4;
    if (idx < ne4) {
        const float4 v = *(const float4*)&edge_feat[idx * 4];
        ushort4 o; o.x = f2b(v.x); o.y = f2b(v.y); o.z = f2b(v.z); o.w = f2b(v.w);
        *(ushort4*)&eb[idx * 4] = o;
        return;
    }
    idx -= ne4;
    if (idx < 2 * E) {
        const int tgt = (idx < E) ? edge_index[E + idx] : edge_index[idx - E];
        atomicAdd(&cnti[tgt], 1);
    }
}

// ---- multi-block exclusive scan: scan1 (block-local) -> scan2 (block totals) -> scan3 (add) ----
__global__ void __launch_bounds__(256)
scan1(const int* __restrict__ cnti, int* __restrict__ off, int* __restrict__ btot, int N)
{
    __shared__ int sh[SCB];
    __shared__ int tsum[256];
    const int t = threadIdx.x;
    const int base = blockIdx.x * SCB;
    for (int i = t; i < SCB; i += 256) { int g = base + i; sh[i] = (g < N) ? cnti[g] : 0; }
    __syncthreads();
    int loc[8], s = 0;
#pragma unroll
    for (int k = 0; k < 8; k++) { loc[k] = s; s += sh[t * 8 + k]; }
    tsum[t] = s;
    __syncthreads();
    for (int d = 1; d < 256; d <<= 1) {
        int v = (t >= d) ? tsum[t - d] : 0;
        __syncthreads();
        tsum[t] += v;
        __syncthreads();
    }
    const int pre = (t > 0) ? tsum[t - 1] : 0;
#pragma unroll
    for (int k = 0; k < 8; k++) { int g = base + t * 8 + k; if (g < N) off[g] = pre + loc[k]; }
    if (t == 255) btot[blockIdx.x] = tsum[255];
}
__global__ void __launch_bounds__(64)
scan2(int* __restrict__ btot, int nb)
{
    if (threadIdx.x == 0) {
        int s = 0;
        for (int b = 0; b < nb; b++) { int c = btot[b]; btot[b] = s; s += c; }
    }
}
__global__ void __launch_bounds__(256)
scan3(int* __restrict__ off, const int* __restrict__ btot, int* __restrict__ cursor, int N)
{
    int i = blockIdx.x * 256 + threadIdx.x;
    if (i < N) { int v = off[i] + btot[i / SCB]; off[i] = v; cursor[i] = v; }
}

// Fused scatter + pose: thread g claims sorted position pos; writes dinfo, p2n, pose row.
__global__ void __launch_bounds__(256)
scatter_pose(const float* __restrict__ T_R, const float* __restrict__ T_t,
             const float* __restrict__ Tij_R, const float* __restrict__ Tij_t,
             const int* __restrict__ edge_index, int* __restrict__ cursor,
             int4* __restrict__ dinfo, int* __restrict__ p2n,
             unsigned short* __restrict__ poseb, int E)
{
    const int g = blockIdx.x * 256 + threadIdx.x;
    if (g >= 2 * E) return;
    const bool fwd = (g < E);
    const int e = fwd ? g : g - E;
    const int ni = edge_index[e];
    const int nj = edge_index[E + e];
    const int tgt = fwd ? nj : ni;
    const int pos = atomicAdd(&cursor[tgt], 1);
    dinfo[pos] = make_int4(fwd ? ni : nj, fwd ? nj : ni, e, tgt);
    p2n[pos] = tgt;

    float Ri[9], Rj[9], TR[9], ti[3], tj[3], Tt[3];
#pragma unroll
    for (int q = 0; q < 9; q++) { Ri[q] = T_R[9*ni+q]; Rj[q] = T_R[9*nj+q]; TR[q] = Tij_R[9*e+q]; }
#pragma unroll
    for (int q = 0; q < 3; q++) { ti[q] = T_t[3*ni+q]; tj[q] = T_t[3*nj+q]; Tt[q] = Tij_t[3*e+q]; }
    float A[9];
    mul33_abt(Rj, Ri, A);   // A = Rj * Ri^T
    float Re[9], te[3];
    if (fwd) {
        mul33_abt(A, TR, Re);   // Reij = A * TR^T
#pragma unroll
        for (int r = 0; r < 3; r++)
            te[r] = tj[r]
                  - (A[3*r+0]*ti[0] + A[3*r+1]*ti[1] + A[3*r+2]*ti[2])
                  - (Re[3*r+0]*Tt[0] + Re[3*r+1]*Tt[1] + Re[3*r+2]*Tt[2]);
    } else {
#pragma unroll
        for (int r = 0; r < 3; r++)
#pragma unroll
            for (int c = 0; c < 3; c++)
                Re[3*r+c] = A[r]*TR[c] + A[3+r]*TR[3+c] + A[6+r]*TR[6+c];  // A^T * TR
        const float d0 = Tt[0]-tj[0], d1 = Tt[1]-tj[1], d2 = Tt[2]-tj[2];
#pragma unroll
        for (int r = 0; r < 3; r++)
            te[r] = ti[r] + A[r]*d0 + A[3+r]*d1 + A[6+r]*d2;
    }
    short8 p0, p1;
#pragma unroll
    for (int r = 0; r < 2; r++) {
        p0[4*r+0] = (short)f2b(Re[3*r+0]);
        p0[4*r+1] = (short)f2b(Re[3*r+1]);
        p0[4*r+2] = (short)f2b(Re[3*r+2]);
        p0[4*r+3] = (short)f2b(te[r]);
    }
    p1[0] = (short)f2b(Re[6]); p1[1] = (short)f2b(Re[7]);
    p1[2] = (short)f2b(Re[8]); p1[3] = (short)f2b(te[2]);
    p1[4] = 0; p1[5] = 0; p1[6] = 0; p1[7] = 0;
    *(short8*)(poseb + (size_t)pos * 16) = p0;
    *(short8*)(poseb + (size_t)pos * 16 + 8) = p1;
}

// Edge MLP + fused mean-aggregation. GEMM1 flipped, GEMM2 normal (r8 structure).
// Epilogue: per-node fp32 accumulation in LDS (aliased with h1 scratch) -> sums[n].
__global__ void __launch_bounds__(256, 2)
edge_kernel(const unsigned short* __restrict__ xb, const unsigned short* __restrict__ eb,
            const unsigned short* __restrict__ poseb, const int4* __restrict__ dinfo,
            const int* __restrict__ p2n, const int* __restrict__ off,
            const int* __restrict__ cnti,
            const unsigned short* __restrict__ W1b, const float* __restrict__ b1,
            const unsigned short* __restrict__ W2b, const float* __restrict__ b2,
            float* __restrict__ sums, int E)
{
    __shared__ __align__(16) char smem[4 * 64 * P1 * 2];   // h1 scratch, aliased as nacc
    __shared__ int sinfo[2];
    unsigned short* h1s = (unsigned short*)smem;
    float* nacc = (float*)smem;
    const int tid = threadIdx.x;
    const int wv = tid >> 6, lane = tid & 63;
    const int nl = lane & 15, quad = lane >> 4;
    const int D0blk = blockIdx.x * MT;
    const int D0 = D0blk + wv * 64;
    const int laneoff = quad * 128 + nl * 8;
    const int twoE = 2 * E;
    unsigned short* hw = h1s + wv * 64 * P1;

    if (tid == 0) {
        sinfo[0] = p2n[D0blk];
        sinfo[1] = p2n[min(D0blk + MT - 1, twoE - 1)];
    }

    int s1[4], s2[4], ee[4], pp[4];
#pragma unroll
    for (int rt = 0; rt < 4; rt++) {
        int p = D0 + rt * 16 + nl;
        if (p >= twoE) p = twoE - 1;
        pp[rt] = p;
        const int4 di = dinfo[p];
        s1[rt] = di.x; s2[rt] = di.y; ee[rt] = di.z;
    }

    // GEMM1 flipped: acc[rt][At] = h1^T tile; A=W1-frag, B=f-frag. A+W double-buffered.
    f32x4 acc[4][8];
#pragma unroll
    for (int rt = 0; rt < 4; rt++)
#pragma unroll
        for (int At = 0; At < 8; At++) acc[rt][At] = (f32x4)0.f;

    short8 af[2][4], wf[2][8];
#pragma unroll
    for (int rt = 0; rt < 4; rt++)
        af[0][rt] = *(const short8*)(xb + (size_t)s1[rt] * ND + quad * 8);
#pragma unroll
    for (int nt = 0; nt < 8; nt++)
        wf[0][nt] = *(const short8*)(W1b + nt * 512 + laneoff);

#pragma unroll
    for (int kc = 0; kc < 6; kc++) {
        const int cur = kc & 1, nxt = cur ^ 1;
        if (kc < 5) {
#pragma unroll
            for (int rt = 0; rt < 4; rt++) {
                switch (kc + 1) {
                case 1: af[nxt][rt] = *(const short8*)(xb + (size_t)s1[rt] * ND + 32 + quad * 8); break;
                case 2: af[nxt][rt] = *(const short8*)(xb + (size_t)s2[rt] * ND + quad * 8); break;
                case 3: af[nxt][rt] = *(const short8*)(xb + (size_t)s2[rt] * ND + 32 + quad * 8); break;
                case 4: af[nxt][rt] = *(const short8*)(eb + (size_t)ee[rt] * ED + quad * 8); break;
                default: af[nxt][rt] = (quad < 2) ? *(const short8*)(poseb + (size_t)pp[rt] * 16 + quad * 8)
                                                  : (short8)(short)0; break;
                }
            }
#pragma unroll
            for (int nt = 0; nt < 8; nt++)
                wf[nxt][nt] = *(const short8*)(W1b + ((kc + 1) * 8 + nt) * 512 + laneoff);
        }
#pragma unroll
        for (int At = 0; At < 8; At++)
#pragma unroll
            for (int rt = 0; rt < 4; rt++)
                acc[rt][At] = __builtin_amdgcn_mfma_f32_16x16x32_bf16(wf[cur][At], af[cur][rt], acc[rt][At], 0, 0, 0);
    }

    // h1 epilogue: packed b64 LDS writes (P1=132: measured 0-conflict pattern)
#pragma unroll
    for (int At = 0; At < 8; At++) {
        const f32x4 bv = *(const f32x4*)&b1[At * 16 + quad * 4];
#pragma unroll
        for (int rt = 0; rt < 4; rt++) {
            unsigned int lo = (unsigned int)f2b(fmaxf(acc[rt][At][0] + bv[0], 0.f))
                            | ((unsigned int)f2b(fmaxf(acc[rt][At][1] + bv[1], 0.f)) << 16);
            unsigned int hi = (unsigned int)f2b(fmaxf(acc[rt][At][2] + bv[2], 0.f))
                            | ((unsigned int)f2b(fmaxf(acc[rt][At][3] + bv[3], 0.f)) << 16);
            uint2 pk; pk.x = lo; pk.y = hi;
            *(uint2*)&hw[(rt * 16 + nl) * P1 + At * 16 + quad * 4] = pk;
        }
    }
    asm volatile("s_waitcnt lgkmcnt(0)" ::: "memory");

    // GEMM2 normal: A = h1 rows (2x b64 LDS reads), B = W2-frag (dbuf).
#pragma unroll
    for (int rt = 0; rt < 4; rt++)
#pragma unroll
        for (int nt = 0; nt < 8; nt++) acc[rt][nt] = (f32x4)0.f;
#pragma unroll
    for (int nt = 0; nt < 8; nt++)
        wf[0][nt] = *(const short8*)(W2b + nt * 512 + laneoff);
#pragma unroll
    for (int kc = 0; kc < 4; kc++) {
        union { short8 s; uint2 u[2]; } hf[4];
#pragma unroll
        for (int rt = 0; rt < 4; rt++) {
            const unsigned short* hp = &hw[(rt * 16 + nl) * P1 + kc * 32 + quad * 8];
            hf[rt].u[0] = *(const uint2*)hp;
            hf[rt].u[1] = *(const uint2*)(hp + 4);
        }
        const int cur = kc & 1, nxt = cur ^ 1;
        if (kc < 3) {
#pragma unroll
            for (int nt = 0; nt < 8; nt++)
                wf[nxt][nt] = *(const short8*)(W2b + ((kc + 1) * 8 + nt) * 512 + laneoff);
        }
#pragma unroll
        for (int nt = 0; nt < 8; nt++)
#pragma unroll
            for (int rt = 0; rt < 4; rt++)
                acc[rt][nt] = __builtin_amdgcn_mfma_f32_16x16x32_bf16(hf[rt].s, wf[cur][nt], acc[rt][nt], 0, 0, 0);
    }

    // ---- fused aggregation epilogue ----
    __syncthreads();                       // all waves done with h1 region
    const int n_first = sinfo[0];
    const int nspan = sinfo[1] - n_first + 1;
    const bool fb = (nspan > NACC_CAP);    // pathological fallback (never for Poisson(20))
    if (!fb)
        for (int i = tid; i < nspan * NACCP; i += 256) nacc[i] = 0.f;
    __syncthreads();

    {
        float bias2[8];
#pragma unroll
        for (int nt = 0; nt < 8; nt++) bias2[nt] = b2[nt * 16 + nl];
#pragma unroll
        for (int rt = 0; rt < 4; rt++) {
            const int p2b = D0 + rt * 16 + quad * 4;
            if (p2b >= twoE) continue;
            const int4 nd = *(const int4*)(p2n + p2b);
            const int nvals = min(4, twoE - p2b);
            if (nvals == 4 && nd.x == nd.w) {
                const int row = nd.x - n_first;
#pragma unroll
                for (int nt = 0; nt < 8; nt++) {
                    const f32x4 a = acc[rt][nt];
                    const float bb = bias2[nt];
                    const float v = fmaxf(a[0] + bb, 0.f) + fmaxf(a[1] + bb, 0.f)
                                  + fmaxf(a[2] + bb, 0.f) + fmaxf(a[3] + bb, 0.f);
                    if (fb) unsafeAtomicAdd(&sums[(size_t)nd.x * HD + nt * 16 + nl], v);
                    else    atomicAdd(&nacc[row * NACCP + nt * 16 + nl], v);
                }
            } else {
                const int nda[4] = {nd.x, nd.y, nd.z, nd.w};
                for (int r = 0; r < nvals; r++) {
                    const int node = nda[r];
                    const int row = node - n_first;
#pragma unroll
                    for (int nt = 0; nt < 8; nt++) {
                        const float v = fmaxf(acc[rt][nt][r] + bias2[nt], 0.f);
                        if (fb) unsafeAtomicAdd(&sums[(size_t)node * HD + nt * 16 + nl], v);
                        else    atomicAdd(&nacc[row * NACCP + nt * 16 + nl], v);
                    }
                }
            }
        }
    }
    __syncthreads();

    if (!fb) {
        for (int idx = tid; idx < nspan * HD; idx += 256) {
            const int l = idx >> 7, col = idx & 127;
            const int n = n_first + l;
            const float v = nacc[l * NACCP + col];
            const int st = off[n];
            const int en = st + cnti[n];
            if (st >= D0blk && en <= D0blk + MT)
                sums[(size_t)n * HD + col] = v;           // node fully inside this block
            else
                unsafeAtomicAdd(&sums[(size_t)n * HD + col], v);  // straddler
        }
    }
}

__global__ void __launch_bounds__(256)
node_kernel(const float* __restrict__ xfeat, const float* __restrict__ T_R,
            const float* __restrict__ T_t, const float* __restrict__ u,
            const int* __restrict__ batch,
            const unsigned short* __restrict__ W3b, const float* __restrict__ b3,
            const unsigned short* __restrict__ W4b, const float* __restrict__ b4,
            const float* __restrict__ sums, const int* __restrict__ cnti,
            float* __restrict__ out, int Nn)
{
    __shared__ unsigned short gbuf[TDN * GP];
    __shared__ unsigned short hid[TDN * HP];
    __shared__ float obuf[TDN * OP];
    const int tid = threadIdx.x;
    const int wv = tid >> 6, lane = tid & 63;
    const int n0 = blockIdx.x * TDN;
    const int nn = min(TDN, Nn - n0);

    // aggr = sums / deg (fp32 -> bf16), plain column layout
    for (int idx = tid; idx < TDN * 64; idx += 256) {
        const int d = idx >> 6, c2 = idx & 63;
        if (d < nn) {
            const int n = n0 + d;
            const float2 v = *(const float2*)&sums[(size_t)n * HD + 2 * c2];
            const float inv = 1.0f / (float)max(cnti[n], 1);
            const unsigned int pk = (unsigned int)f2b(v.x * inv) | ((unsigned int)f2b(v.y * inv) << 16);
            *(unsigned int*)&gbuf[d * GP + 2 * c2] = pk;
        }
    }
    for (int idx = tid; idx < TDN * 24; idx += 256) {
        const int d = idx / 24;
        if (d < nn) {
            const int n = n0 + d;
            const int c4 = (idx % 24) * 4;
            float4 v;
            if (c4 < 64) v = *(const float4*)&xfeat[(size_t)n * ND + c4];
            else         v = *(const float4*)&u[(size_t)batch[n] * GD + (c4 - 64)];
            ushort4 o; o.x = f2b(v.x); o.y = f2b(v.y); o.z = f2b(v.z); o.w = f2b(v.w);
            *(ushort4*)&gbuf[d * GP + 128 + c4] = o;
        }
    }
    __syncthreads();

    const int nl = lane & 15, quad = lane >> 4;
    const int laneoff = quad * 128 + nl * 8;

    // GEMM3: 16 rows, K=224; wave wv -> n-tiles {2wv, 2wv+1}
    f32x4 acc3[2];
    acc3[0] = (f32x4)0.f; acc3[1] = (f32x4)0.f;
#pragma unroll
    for (int kc = 0; kc < 7; kc++) {
        short8 A0 = *(const short8*)&gbuf[nl * GP + kc * 32 + quad * 8];
#pragma unroll
        for (int t = 0; t < 2; t++) {
            short8 B = *(const short8*)(W3b + (kc * 8 + wv * 2 + t) * 512 + laneoff);
            acc3[t] = __builtin_amdgcn_mfma_f32_16x16x32_bf16(A0, B, acc3[t], 0, 0, 0);
        }
    }
#pragma unroll
    for (int t = 0; t < 2; t++) {
        const int col = (wv * 2 + t) * 16 + nl;
        const float bb = b3[col];
#pragma unroll
        for (int r = 0; r < 4; r++)
            hid[(quad * 4 + r) * HP + col] = f2b(fmaxf(acc3[t][r] + bb, 0.f));
    }
    __syncthreads();

    // GEMM4: K=128, N=80 (wave w -> nt=w; wave0 also nt=4)
    f32x4 acc4[2];
    acc4[0] = (f32x4)0.f; acc4[1] = (f32x4)0.f;
    const int nt1 = (wv == 0) ? 4 : -1;
#pragma unroll
    for (int kc = 0; kc < 4; kc++) {
        short8 A0 = *(const short8*)&hid[nl * HP + kc * 32 + quad * 8];
        short8 B0 = *(const short8*)(W4b + (kc * 5 + wv) * 512 + laneoff);
        acc4[0] = __builtin_amdgcn_mfma_f32_16x16x32_bf16(A0, B0, acc4[0], 0, 0, 0);
        if (nt1 >= 0) {
            short8 B1 = *(const short8*)(W4b + (kc * 5 + nt1) * 512 + laneoff);
            acc4[1] = __builtin_amdgcn_mfma_f32_16x16x32_bf16(A0, B1, acc4[1], 0, 0, 0);
        }
    }
    {
        const int col0 = wv * 16 + nl;
        const float bb0 = (col0 < NOUT) ? b4[col0] : 0.f;
#pragma unroll
        for (int r = 0; r < 4; r++)
            obuf[(quad * 4 + r) * OP + col0] = acc4[0][r] + bb0;
        if (nt1 >= 0) {
            const int col1 = nt1 * 16 + nl;
            const float bb1 = (col1 < NOUT) ? b4[col1] : 0.f;
#pragma unroll
            for (int r = 0; r < 4; r++)
                obuf[(quad * 4 + r) * OP + col1] = acc4[1][r] + bb1;
        }
    }
    __syncthreads();

    // xfeat residual
    for (int idx = tid; idx < TDN * ND; idx += 256) {
        const int d = idx >> 6, c = idx & 63;
        if (d < nn) {
            const int n = n0 + d;
            out[(size_t)n * OUTC + c] = xfeat[(size_t)n * ND + c] + obuf[d * OP + c];
        }
    }
    // SE(3) epilogue
    if (tid < nn) {
        const int n = n0 + tid;
        const float r0 = obuf[tid*OP + 64], r1 = obuf[tid*OP + 65], r2 = obuf[tid*OP + 66];
        float p0 = obuf[tid*OP + 67], p1 = obuf[tid*OP + 68], p2 = obuf[tid*OP + 69];
        const float th0 = sqrtf(p0*p0 + p1*p1 + p2*p2);
        const float s = PI_F * tanhf(th0 / PI_F) / (th0 + 1e-8f);
        p0 *= s; p1 *= s; p2 *= s;
        const float pp = p0*p0 + p1*p1 + p2*p2;
        const float th = sqrtf(pp + 1e-12f);
        float a, b, c;
        if (th < 1e-4f) { a = 1.f - pp/6.f; b = 0.5f - pp/24.f; c = 1.f/6.f - pp/120.f; }
        else { const float sn = sinf(th), cs = cosf(th); a = sn/th; b = (1.f-cs)/pp; c = (th-sn)/(pp*th); }
        float Rd[9], V[9];
        Rd[0]=1.f+b*(p0*p0-pp); Rd[1]=-a*p2+b*p0*p1; Rd[2]= a*p1+b*p0*p2;
        Rd[3]= a*p2+b*p1*p0;    Rd[4]=1.f+b*(p1*p1-pp); Rd[5]=-a*p0+b*p1*p2;
        Rd[6]=-a*p1+b*p2*p0;    Rd[7]= a*p0+b*p2*p1;  Rd[8]=1.f+b*(p2*p2-pp);
        V[0]=1.f+c*(p0*p0-pp);  V[1]=-b*p2+c*p0*p1;   V[2]= b*p1+c*p0*p2;
        V[3]= b*p2+c*p1*p0;     V[4]=1.f+c*(p1*p1-pp); V[5]=-b*p0+c*p1*p2;
        V[6]=-b*p1+c*p2*p0;     V[7]= b*p0+c*p2*p1;   V[8]=1.f+c*(p2*p2-pp);
        const float td0 = V[0]*r0 + V[1]*r1 + V[2]*r2;
        const float td1 = V[3]*r0 + V[4]*r1 + V[5]*r2;
        const float td2 = V[6]*r0 + V[7]*r1 + V[8]*r2;
        float TRn[9], Ttn[3];
#pragma unroll
        for (int q = 0; q < 9; q++) TRn[q] = T_R[9*n+q];
#pragma unroll
        for (int q = 0; q < 3; q++) Ttn[q] = T_t[3*n+q];
        float* o = out + (size_t)n * OUTC + 64;
#pragma unroll
        for (int r = 0; r < 3; r++)
#pragma unroll
            for (int cc = 0; cc < 3; cc++)
                o[3*r+cc] = Rd[3*r+0]*TRn[cc] + Rd[3*r+1]*TRn[3+cc] + Rd[3*r+2]*TRn[6+cc];
        o[9]  = Rd[0]*Ttn[0] + Rd[1]*Ttn[1] + Rd[2]*Ttn[2] + td0;
        o[10] = Rd[3]*Ttn[0] + Rd[4]*Ttn[1] + Rd[5]*Ttn[2] + td1;
        o[11] = Rd[6]*Ttn[0] + Rd[7]*Ttn[1] + Rd[8]*Ttn[2] + td2;
        o[12] = sqrtf(pp);
    }
}

extern "C" void kernel_launch(void* const* d_in, const int* in_sizes, int n_in,
                              void* d_out, int out_size, void* d_ws, size_t ws_size,
                              hipStream_t stream)
{
    const float* xfeat     = (const float*)d_in[0];
    const float* T_R       = (const float*)d_in[1];
    const float* T_t       = (const float*)d_in[2];
    const float* edge_feat = (const float*)d_in[3];
    const float* Tij_R     = (const float*)d_in[4];
    const float* Tij_t     = (const float*)d_in[5];
    const float* u         = (const float*)d_in[6];
    const int*   edge_index= (const int*)d_in[7];
    const int*   batch     = (const int*)d_in[8];
    const float* W1 = (const float*)d_in[9],  *b1 = (const float*)d_in[10];
    const float* W2 = (const float*)d_in[11], *b2 = (const float*)d_in[12];
    const float* W3 = (const float*)d_in[13], *b3 = (const float*)d_in[14];
    const float* W4 = (const float*)d_in[15], *b4 = (const float*)d_in[16];
    const int N = in_sizes[0] / ND;
    const int E = in_sizes[3] / ED;

    // ws: weights | xb | eb | poseb | dinfo | p2n(+pad) | sums | cnti | off | cursor | btot
    char* p = (char*)d_ws;
    unsigned short* W1b = (unsigned short*)p;   p += (size_t)K1PAD * HD * 2;
    unsigned short* W2b = (unsigned short*)p;   p += (size_t)HD * HD * 2;
    unsigned short* W3b = (unsigned short*)p;   p += (size_t)KG * HD * 2;
    unsigned short* W4b = (unsigned short*)p;   p += (size_t)HD * N4P * 2;
    unsigned short* xb  = (unsigned short*)p;   p += (size_t)N * ND * 2;
    unsigned short* ebf = (unsigned short*)p;   p += (size_t)E * ED * 2;
    unsigned short* poseb = (unsigned short*)p; p += (size_t)2 * E * 16 * 2;
    int4* dinfo = (int4*)p;                     p += (size_t)2 * E * 16;
    int* p2n = (int*)p;                         p += ((size_t)2 * E + 8) * 4;
    float* sums = (float*)p;                    p += (size_t)N * HD * 4;
    int* cnti = (int*)p;                        p += (size_t)N * 4;
    int* off  = (int*)p;                        p += (size_t)N * 4;
    int* cursor = (int*)p;                      p += (size_t)N * 4;
    int* btot = (int*)p;

    hipMemsetAsync(cnti, 0, (size_t)N * 4, stream);
    hipMemsetAsync(sums, 0, (size_t)N * HD * 4, stream);
    const int prepn = K1PAD*HD + HD*HD + KG*HD + HD*N4P + N*ND/4 + E*ED/4 + 2*E;
    prep<<<(prepn + 255) / 256, 256, 0, stream>>>(W1, W2, W3, W4, xfeat, edge_feat,
                                                  edge_index, W1b, W2b, W3b, W4b,
                                                  xb, ebf, cnti, N, E);
    const int nsb = (N + SCB - 1) / SCB;
    scan1<<<nsb, 256, 0, stream>>>(cnti, off, btot, N);
    scan2<<<1, 64, 0, stream>>>(btot, nsb);
    scan3<<<(N + 255) / 256, 256, 0, stream>>>(off, btot, cursor, N);
    scatter_pose<<<(2*E + 255) / 256, 256, 0, stream>>>(T_R, T_t, Tij_R, Tij_t,
                                                        edge_index, cursor, dinfo, p2n, poseb, E);
    const int ebk = (2 * E + MT - 1) / MT;
    edge_kernel<<<ebk, 256, 0, stream>>>(xb, ebf, poseb, dinfo, p2n, off, cnti,
                                         W1b, b1, W2b, b2, sums, E);
    const int nb = (N + TDN - 1) / TDN;
    node_kernel<<<nb, 256, 0, stream>>>(xfeat, T_R, T_t, u, batch, W3b, b3, W4b, b4,
                                        sums, cnti, (float*)d_out, N);
}

// Round 10
// 265.607 us; speedup vs baseline: 1.2301x; 1.2301x over previous
//
#include <hip/hip_runtime.h>
#include <math.h>

#define ND 64
#define ED 32
#define GD 32
#define HD 128
#define DOF 6
#define K1 172      // 2*ND + ED + 12
#define K1PAD 192   // padded to 6 chunks of 32
#define KG 224      // HD + ND + GD (7 chunks of 32)
#define N4P 80      // W4 cols padded 70 -> 80 (5 n-tiles)
#define NOUT 70
#define OUTC 77
#define MT 256      // directions per edge block (4 waves x 64)
#define P1 132      // edge h1 LDS pitch (bf16): b64 write/read pattern measured 0-conflict (r9)
#define TDN 16      // nodes per node block
#define GP 232      // node gbuf pitch (bf16)
#define HP 136      // node hidden pitch (bf16)
#define OP 84       // node obuf pitch (fp32)
#define SCB 2048    // scan block chunk
#define PI_F 3.14159265358979f

typedef short short8 __attribute__((ext_vector_type(8)));
typedef float f32x4  __attribute__((ext_vector_type(4)));

__device__ __forceinline__ unsigned short f2b(float f) {
    unsigned int u = __float_as_uint(f);
    u += 0x7fffu + ((u >> 16) & 1u);
    return (unsigned short)(u >> 16);
}
__device__ __forceinline__ float b2f(unsigned short b) {
    return __uint_as_float(((unsigned int)b) << 16);
}
__device__ __forceinline__ void mul33_abt(const float* A, const float* B, float* C) {
#pragma unroll
    for (int r = 0; r < 3; r++)
#pragma unroll
        for (int c = 0; c < 3; c++)
            C[3*r+c] = A[3*r+0]*B[3*c+0] + A[3*r+1]*B[3*c+1] + A[3*r+2]*B[3*c+2];
}

// Pack weights to MFMA fragment layout + bf16-convert xfeat/edge_feat + degree count.
// frag: off(k,n) = (((kc*NT + nt)*4 + quad)*16 + nl)*8 + j.
// W3's first 128 K-rows permuted for the swizzled hbuf position layout (pos p <- col (p&7)*16+(p>>3)).
__global__ void __launch_bounds__(256)
prep(const float* __restrict__ W1, const float* __restrict__ W2,
     const float* __restrict__ W3, const float* __restrict__ W4,
     const float* __restrict__ xfeat, const float* __restrict__ edge_feat,
     const int* __restrict__ edge_index,
     unsigned short* __restrict__ W1b, unsigned short* __restrict__ W2b,
     unsigned short* __restrict__ W3b, unsigned short* __restrict__ W4b,
     unsigned short* __restrict__ xb, unsigned short* __restrict__ eb,
     int* __restrict__ cnti, int N, int E)
{
    int idx = blockIdx.x * 256 + threadIdx.x;
    if (idx < K1PAD * HD) {
        int k = idx >> 7, n = idx & 127;
        float v = (k < K1) ? W1[k * HD + n] : 0.f;
        int kc = k >> 5, kr = k & 31, q = kr >> 3, j = kr & 7;
        W1b[(((kc * 8 + (n >> 4)) * 4 + q) * 16 + (n & 15)) * 8 + j] = f2b(v);
        return;
    }
    idx -= K1PAD * HD;
    if (idx < HD * HD) {
        int k = idx >> 7, n = idx & 127;
        int kc = k >> 5, kr = k & 31, q = kr >> 3, j = kr & 7;
        W2b[(((kc * 8 + (n >> 4)) * 4 + q) * 16 + (n & 15)) * 8 + j] = f2b(W2[k * HD + n]);
        return;
    }
    idx -= HD * HD;
    if (idx < KG * HD) {
        int k = idx >> 7, n = idx & 127;
        int sk = (k < HD) ? ((k & 7) * 16 + (k >> 3)) : k;   // un-swizzle aggr rows
        int kc = k >> 5, kr = k & 31, q = kr >> 3, j = kr & 7;
        W3b[(((kc * 8 + (n >> 4)) * 4 + q) * 16 + (n & 15)) * 8 + j] = f2b(W3[sk * HD + n]);
        return;
    }
    idx -= KG * HD;
    if (idx < HD * N4P) {
        int k = idx / N4P, n = idx % N4P;
        float v = (n < NOUT) ? W4[k * NOUT + n] : 0.f;
        int kc = k >> 5, kr = k & 31, q = kr >> 3, j = kr & 7;
        W4b[(((kc * 5 + (n >> 4)) * 4 + q) * 16 + (n & 15)) * 8 + j] = f2b(v);
        return;
    }
    idx -= HD * N4P;
    const int nx4 = N * ND / 4;
    if (idx < nx4) {
        const float4 v = *(const float4*)&xfeat[idx * 4];
        ushort4 o; o.x = f2b(v.x); o.y = f2b(v.y); o.z = f2b(v.z); o.w = f2b(v.w);
        *(ushort4*)&xb[idx * 4] = o;
        return;
    }
    idx -= nx4;
    const int ne4 = E * ED / 4;
    if (idx < ne4) {
        const float4 v = *(const float4*)&edge_feat[idx * 4];
        ushort4 o; o.x = f2b(v.x); o.y = f2b(v.y); o.z = f2b(v.z); o.w = f2b(v.w);
        *(ushort4*)&eb[idx * 4] = o;
        return;
    }
    idx -= ne4;
    if (idx < 2 * E) {
        const int tgt = (idx < E) ? edge_index[E + idx] : edge_index[idx - E];
        atomicAdd(&cnti[tgt], 1);
    }
}

// ---- multi-block exclusive scan ----
__global__ void __launch_bounds__(256)
scan1(const int* __restrict__ cnti, int* __restrict__ off, int* __restrict__ btot, int N)
{
    __shared__ int sh[SCB];
    __shared__ int tsum[256];
    const int t = threadIdx.x;
    const int base = blockIdx.x * SCB;
    for (int i = t; i < SCB; i += 256) { int g = base + i; sh[i] = (g < N) ? cnti[g] : 0; }
    __syncthreads();
    int loc[8], s = 0;
#pragma unroll
    for (int k = 0; k < 8; k++) { loc[k] = s; s += sh[t * 8 + k]; }
    tsum[t] = s;
    __syncthreads();
    for (int d = 1; d < 256; d <<= 1) {
        int v = (t >= d) ? tsum[t - d] : 0;
        __syncthreads();
        tsum[t] += v;
        __syncthreads();
    }
    const int pre = (t > 0) ? tsum[t - 1] : 0;
#pragma unroll
    for (int k = 0; k < 8; k++) { int g = base + t * 8 + k; if (g < N) off[g] = pre + loc[k]; }
    if (t == 255) btot[blockIdx.x] = tsum[255];
}
__global__ void __launch_bounds__(64)
scan2(int* __restrict__ btot, int nb)
{
    if (threadIdx.x == 0) {
        int s = 0;
        for (int b = 0; b < nb; b++) { int c = btot[b]; btot[b] = s; s += c; }
    }
}
__global__ void __launch_bounds__(256)
scan3(int* __restrict__ off, const int* __restrict__ btot, int* __restrict__ cursor, int N)
{
    int i = blockIdx.x * 256 + threadIdx.x;
    if (i < N) { int v = off[i] + btot[i / SCB]; off[i] = v; cursor[i] = v; }
}

// Fused scatter + pose: thread g claims sorted position pos, writes dinfo + bf16 pose row.
__global__ void __launch_bounds__(256)
scatter_pose(const float* __restrict__ T_R, const float* __restrict__ T_t,
             const float* __restrict__ Tij_R, const float* __restrict__ Tij_t,
             const int* __restrict__ edge_index, int* __restrict__ cursor,
             int4* __restrict__ dinfo, unsigned short* __restrict__ poseb, int E)
{
    const int g = blockIdx.x * 256 + threadIdx.x;
    if (g >= 2 * E) return;
    const bool fwd = (g < E);
    const int e = fwd ? g : g - E;
    const int ni = edge_index[e];
    const int nj = edge_index[E + e];
    const int tgt = fwd ? nj : ni;
    const int pos = atomicAdd(&cursor[tgt], 1);
    dinfo[pos] = make_int4(fwd ? ni : nj, fwd ? nj : ni, e, g);

    float Ri[9], Rj[9], TR[9], ti[3], tj[3], Tt[3];
#pragma unroll
    for (int q = 0; q < 9; q++) { Ri[q] = T_R[9*ni+q]; Rj[q] = T_R[9*nj+q]; TR[q] = Tij_R[9*e+q]; }
#pragma unroll
    for (int q = 0; q < 3; q++) { ti[q] = T_t[3*ni+q]; tj[q] = T_t[3*nj+q]; Tt[q] = Tij_t[3*e+q]; }
    float A[9];
    mul33_abt(Rj, Ri, A);   // A = Rj * Ri^T
    float Re[9], te[3];
    if (fwd) {
        mul33_abt(A, TR, Re);   // Reij = A * TR^T
#pragma unroll
        for (int r = 0; r < 3; r++)
            te[r] = tj[r]
                  - (A[3*r+0]*ti[0] + A[3*r+1]*ti[1] + A[3*r+2]*ti[2])
                  - (Re[3*r+0]*Tt[0] + Re[3*r+1]*Tt[1] + Re[3*r+2]*Tt[2]);
    } else {
#pragma unroll
        for (int r = 0; r < 3; r++)
#pragma unroll
            for (int c = 0; c < 3; c++)
                Re[3*r+c] = A[r]*TR[c] + A[3+r]*TR[3+c] + A[6+r]*TR[6+c];  // A^T * TR
        const float d0 = Tt[0]-tj[0], d1 = Tt[1]-tj[1], d2 = Tt[2]-tj[2];
#pragma unroll
        for (int r = 0; r < 3; r++)
            te[r] = ti[r] + A[r]*d0 + A[3+r]*d1 + A[6+r]*d2;
    }
    short8 p0, p1;
#pragma unroll
    for (int r = 0; r < 2; r++) {
        p0[4*r+0] = (short)f2b(Re[3*r+0]);
        p0[4*r+1] = (short)f2b(Re[3*r+1]);
        p0[4*r+2] = (short)f2b(Re[3*r+2]);
        p0[4*r+3] = (short)f2b(te[r]);
    }
    p1[0] = (short)f2b(Re[6]); p1[1] = (short)f2b(Re[7]);
    p1[2] = (short)f2b(Re[8]); p1[3] = (short)f2b(te[2]);
    p1[4] = 0; p1[5] = 0; p1[6] = 0; p1[7] = 0;
    *(short8*)(poseb + (size_t)pos * 16) = p0;
    *(short8*)(poseb + (size_t)pos * 16 + 8) = p1;
}

// Barrier-free edge MLP (r8 structure): GEMM1 flipped (packed b64 h1 writes, P1=132 0-conflict),
// GEMM2 normal (2x b64 LDS reads -> swizzled coalesced 16B h2 stores). A + W double-buffered.
__global__ void __launch_bounds__(256, 2)
edge_kernel(const unsigned short* __restrict__ xb, const unsigned short* __restrict__ eb,
            const unsigned short* __restrict__ poseb, const int4* __restrict__ dinfo,
            const unsigned short* __restrict__ W1b, const float* __restrict__ b1,
            const unsigned short* __restrict__ W2b, const float* __restrict__ b2,
            unsigned short* __restrict__ hbuf, int E)
{
    __shared__ unsigned short h1s[4 * 64 * P1];
    const int tid = threadIdx.x;
    const int wv = tid >> 6, lane = tid & 63;
    const int nl = lane & 15, quad = lane >> 4;
    const int D0 = blockIdx.x * MT + wv * 64;
    const int laneoff = quad * 128 + nl * 8;
    const int twoE = 2 * E;
    unsigned short* hw = h1s + wv * 64 * P1;

    int s1[4], s2[4], ee[4], pp[4];
#pragma unroll
    for (int rt = 0; rt < 4; rt++) {
        int p = D0 + rt * 16 + nl;
        if (p >= twoE) p = twoE - 1;
        pp[rt] = p;
        const int4 di = dinfo[p];
        s1[rt] = di.x; s2[rt] = di.y; ee[rt] = di.z;
    }

    // GEMM1 flipped: acc[rt][At] = h1^T tile; A=W1-frag, B=f-frag. A+W double-buffered.
    f32x4 acc[4][8];
#pragma unroll
    for (int rt = 0; rt < 4; rt++)
#pragma unroll
        for (int At = 0; At < 8; At++) acc[rt][At] = (f32x4)0.f;

    short8 af[2][4], wf[2][8];
#pragma unroll
    for (int rt = 0; rt < 4; rt++)
        af[0][rt] = *(const short8*)(xb + (size_t)s1[rt] * ND + quad * 8);
#pragma unroll
    for (int nt = 0; nt < 8; nt++)
        wf[0][nt] = *(const short8*)(W1b + nt * 512 + laneoff);

#pragma unroll
    for (int kc = 0; kc < 6; kc++) {
        const int cur = kc & 1, nxt = cur ^ 1;
        if (kc < 5) {
#pragma unroll
            for (int rt = 0; rt < 4; rt++) {
                switch (kc + 1) {
                case 1: af[nxt][rt] = *(const short8*)(xb + (size_t)s1[rt] * ND + 32 + quad * 8); break;
                case 2: af[nxt][rt] = *(const short8*)(xb + (size_t)s2[rt] * ND + quad * 8); break;
                case 3: af[nxt][rt] = *(const short8*)(xb + (size_t)s2[rt] * ND + 32 + quad * 8); break;
                case 4: af[nxt][rt] = *(const short8*)(eb + (size_t)ee[rt] * ED + quad * 8); break;
                default: af[nxt][rt] = (quad < 2) ? *(const short8*)(poseb + (size_t)pp[rt] * 16 + quad * 8)
                                                  : (short8)(short)0; break;
                }
            }
#pragma unroll
            for (int nt = 0; nt < 8; nt++)
                wf[nxt][nt] = *(const short8*)(W1b + ((kc + 1) * 8 + nt) * 512 + laneoff);
        }
#pragma unroll
        for (int At = 0; At < 8; At++)
#pragma unroll
            for (int rt = 0; rt < 4; rt++)
                acc[rt][At] = __builtin_amdgcn_mfma_f32_16x16x32_bf16(wf[cur][At], af[cur][rt], acc[rt][At], 0, 0, 0);
    }

    // h1 epilogue: packed b64 LDS writes (P1=132: measured 0-conflict)
#pragma unroll
    for (int At = 0; At < 8; At++) {
        const f32x4 bv = *(const f32x4*)&b1[At * 16 + quad * 4];
#pragma unroll
        for (int rt = 0; rt < 4; rt++) {
            unsigned int lo = (unsigned int)f2b(fmaxf(acc[rt][At][0] + bv[0], 0.f))
                            | ((unsigned int)f2b(fmaxf(acc[rt][At][1] + bv[1], 0.f)) << 16);
            unsigned int hi = (unsigned int)f2b(fmaxf(acc[rt][At][2] + bv[2], 0.f))
                            | ((unsigned int)f2b(fmaxf(acc[rt][At][3] + bv[3], 0.f)) << 16);
            uint2 pk; pk.x = lo; pk.y = hi;
            *(uint2*)&hw[(rt * 16 + nl) * P1 + At * 16 + quad * 4] = pk;
        }
    }
    asm volatile("s_waitcnt lgkmcnt(0)" ::: "memory");

    // GEMM2 normal: A = h1 rows (2x b64 LDS reads), B = W2-frag (dbuf).
#pragma unroll
    for (int rt = 0; rt < 4; rt++)
#pragma unroll
        for (int nt = 0; nt < 8; nt++) acc[rt][nt] = (f32x4)0.f;
#pragma unroll
    for (int nt = 0; nt < 8; nt++)
        wf[0][nt] = *(const short8*)(W2b + nt * 512 + laneoff);
#pragma unroll
    for (int kc = 0; kc < 4; kc++) {
        union { short8 s; uint2 u[2]; } hf[4];
#pragma unroll
        for (int rt = 0; rt < 4; rt++) {
            const unsigned short* hp = &hw[(rt * 16 + nl) * P1 + kc * 32 + quad * 8];
            hf[rt].u[0] = *(const uint2*)hp;
            hf[rt].u[1] = *(const uint2*)(hp + 4);
        }
        const int cur = kc & 1, nxt = cur ^ 1;
        if (kc < 3) {
#pragma unroll
            for (int nt = 0; nt < 8; nt++)
                wf[nxt][nt] = *(const short8*)(W2b + ((kc + 1) * 8 + nt) * 512 + laneoff);
        }
#pragma unroll
        for (int nt = 0; nt < 8; nt++)
#pragma unroll
            for (int rt = 0; rt < 4; rt++)
                acc[rt][nt] = __builtin_amdgcn_mfma_f32_16x16x32_bf16(hf[rt].s, wf[cur][nt], acc[rt][nt], 0, 0, 0);
    }

    // h2: relu + SWIZZLED 16B stores (pos layout p -> col (p&7)*16+(p>>3)), rows sequential
    {
        float bias2[8];
#pragma unroll
        for (int nt = 0; nt < 8; nt++) bias2[nt] = b2[nt * 16 + nl];
#pragma unroll
        for (int rt = 0; rt < 4; rt++)
#pragma unroll
            for (int r = 0; r < 4; r++) {
                const int p2 = D0 + rt * 16 + quad * 4 + r;
                if (p2 < twoE) {
                    short8 hv;
#pragma unroll
                    for (int nt = 0; nt < 8; nt++)
                        hv[nt] = (short)f2b(fmaxf(acc[rt][nt][r] + bias2[nt], 0.f));
                    *(short8*)(hbuf + (size_t)p2 * HD + nl * 8) = hv;
                }
            }
    }
}

__global__ void __launch_bounds__(256)
node_kernel(const float* __restrict__ xfeat, const float* __restrict__ T_R,
            const float* __restrict__ T_t, const float* __restrict__ u,
            const int* __restrict__ batch,
            const unsigned short* __restrict__ W3b, const float* __restrict__ b3,
            const unsigned short* __restrict__ W4b, const float* __restrict__ b4,
            const unsigned short* __restrict__ hbuf, const int* __restrict__ off,
            const int* __restrict__ cnti,
            float* __restrict__ out, int Nn)
{
    __shared__ unsigned short gbuf[TDN * GP];
    __shared__ unsigned short hid[TDN * HP];
    __shared__ float obuf[TDN * OP];
    const int tid = threadIdx.x;
    const int wv = tid >> 6, lane = tid & 63;
    const int n0 = blockIdx.x * TDN;
    const int nn = min(TDN, Nn - n0);

    // gather+mean: node n's rows are CONTIGUOUS [off[n], off[n]+deg) -> streaming reads
#pragma unroll
    for (int i = 0; i < 4; i++) {
        const int d = wv + 4 * i;
        if (d < nn) {
            const int n = n0 + d;
            const int deg = cnti[n];
            const int start = off[n];
            const float inv = 1.0f / (float)max(deg, 1);
            const unsigned short* hp = hbuf + (size_t)start * HD + 2 * lane;
            float a0 = 0.f, a1 = 0.f;
            int k = 0;
            for (; k + 4 <= deg; k += 4) {
                const unsigned int v0 = *(const unsigned int*)(hp);
                const unsigned int v1 = *(const unsigned int*)(hp + HD);
                const unsigned int v2 = *(const unsigned int*)(hp + 2 * HD);
                const unsigned int v3 = *(const unsigned int*)(hp + 3 * HD);
                hp += 4 * HD;
                a0 += b2f((unsigned short)v0) + b2f((unsigned short)v1)
                    + b2f((unsigned short)v2) + b2f((unsigned short)v3);
                a1 += b2f((unsigned short)(v0 >> 16)) + b2f((unsigned short)(v1 >> 16))
                    + b2f((unsigned short)(v2 >> 16)) + b2f((unsigned short)(v3 >> 16));
            }
            for (; k < deg; k++) {
                const unsigned int v0 = *(const unsigned int*)(hp);
                hp += HD;
                a0 += b2f((unsigned short)v0);
                a1 += b2f((unsigned short)(v0 >> 16));
            }
            const unsigned int pk = (unsigned int)f2b(a0 * inv) | ((unsigned int)f2b(a1 * inv) << 16);
            *(unsigned int*)&gbuf[d * GP + 2 * lane] = pk;
        }
    }
    for (int idx = tid; idx < TDN * 24; idx += 256) {
        const int d = idx / 24;
        if (d < nn) {
            const int n = n0 + d;
            const int c4 = (idx % 24) * 4;
            float4 v;
            if (c4 < 64) v = *(const float4*)&xfeat[(size_t)n * ND + c4];
            else         v = *(const float4*)&u[(size_t)batch[n] * GD + (c4 - 64)];
            ushort4 o; o.x = f2b(v.x); o.y = f2b(v.y); o.z = f2b(v.z); o.w = f2b(v.w);
            *(ushort4*)&gbuf[d * GP + 128 + c4] = o;
        }
    }
    __syncthreads();

    const int nl = lane & 15, quad = lane >> 4;
    const int laneoff = quad * 128 + nl * 8;

    // GEMM3: 16 rows, K=224; wave wv -> n-tiles {2wv, 2wv+1}
    f32x4 acc3[2];
    acc3[0] = (f32x4)0.f; acc3[1] = (f32x4)0.f;
#pragma unroll
    for (int kc = 0; kc < 7; kc++) {
        short8 A0 = *(const short8*)&gbuf[nl * GP + kc * 32 + quad * 8];
#pragma unroll
        for (int t = 0; t < 2; t++) {
            short8 B = *(const short8*)(W3b + (kc * 8 + wv * 2 + t) * 512 + laneoff);
            acc3[t] = __builtin_amdgcn_mfma_f32_16x16x32_bf16(A0, B, acc3[t], 0, 0, 0);
        }
    }
#pragma unroll
    for (int t = 0; t < 2; t++) {
        const int col = (wv * 2 + t) * 16 + nl;
        const float bb = b3[col];
#pragma unroll
        for (int r = 0; r < 4; r++)
            hid[(quad * 4 + r) * HP + col] = f2b(fmaxf(acc3[t][r] + bb, 0.f));
    }
    __syncthreads();

    // GEMM4: K=128, N=80 (wave w -> nt=w; wave0 also nt=4)
    f32x4 acc4[2];
    acc4[0] = (f32x4)0.f; acc4[1] = (f32x4)0.f;
    const int nt1 = (wv == 0) ? 4 : -1;
#pragma unroll
    for (int kc = 0; kc < 4; kc++) {
        short8 A0 = *(const short8*)&hid[nl * HP + kc * 32 + quad * 8];
        short8 B0 = *(const short8*)(W4b + (kc * 5 + wv) * 512 + laneoff);
        acc4[0] = __builtin_amdgcn_mfma_f32_16x16x32_bf16(A0, B0, acc4[0], 0, 0, 0);
        if (nt1 >= 0) {
            short8 B1 = *(const short8*)(W4b + (kc * 5 + nt1) * 512 + laneoff);
            acc4[1] = __builtin_amdgcn_mfma_f32_16x16x32_bf16(A0, B1, acc4[1], 0, 0, 0);
        }
    }
    {
        const int col0 = wv * 16 + nl;
        const float bb0 = (col0 < NOUT) ? b4[col0] : 0.f;
#pragma unroll
        for (int r = 0; r < 4; r++)
            obuf[(quad * 4 + r) * OP + col0] = acc4[0][r] + bb0;
        if (nt1 >= 0) {
            const int col1 = nt1 * 16 + nl;
            const float bb1 = (col1 < NOUT) ? b4[col1] : 0.f;
#pragma unroll
            for (int r = 0; r < 4; r++)
                obuf[(quad * 4 + r) * OP + col1] = acc4[1][r] + bb1;
        }
    }
    __syncthreads();

    // xfeat residual
    for (int idx = tid; idx < TDN * ND; idx += 256) {
        const int d = idx >> 6, c = idx & 63;
        if (d < nn) {
            const int n = n0 + d;
            out[(size_t)n * OUTC + c] = xfeat[(size_t)n * ND + c] + obuf[d * OP + c];
        }
    }
    // SE(3) epilogue
    if (tid < nn) {
        const int n = n0 + tid;
        const float r0 = obuf[tid*OP + 64], r1 = obuf[tid*OP + 65], r2 = obuf[tid*OP + 66];
        float p0 = obuf[tid*OP + 67], p1 = obuf[tid*OP + 68], p2 = obuf[tid*OP + 69];
        const float th0 = sqrtf(p0*p0 + p1*p1 + p2*p2);
        const float s = PI_F * tanhf(th0 / PI_F) / (th0 + 1e-8f);
        p0 *= s; p1 *= s; p2 *= s;
        const float pp = p0*p0 + p1*p1 + p2*p2;
        const float th = sqrtf(pp + 1e-12f);
        float a, b, c;
        if (th < 1e-4f) { a = 1.f - pp/6.f; b = 0.5f - pp/24.f; c = 1.f/6.f - pp/120.f; }
        else { const float sn = sinf(th), cs = cosf(th); a = sn/th; b = (1.f-cs)/pp; c = (th-sn)/(pp*th); }
        float Rd[9], V[9];
        Rd[0]=1.f+b*(p0*p0-pp); Rd[1]=-a*p2+b*p0*p1; Rd[2]= a*p1+b*p0*p2;
        Rd[3]= a*p2+b*p1*p0;    Rd[4]=1.f+b*(p1*p1-pp); Rd[5]=-a*p0+b*p1*p2;
        Rd[6]=-a*p1+b*p2*p0;    Rd[7]= a*p0+b*p2*p1;  Rd[8]=1.f+b*(p2*p2-pp);
        V[0]=1.f+c*(p0*p0-pp);  V[1]=-b*p2+c*p0*p1;   V[2]= b*p1+c*p0*p2;
        V[3]= b*p2+c*p1*p0;     V[4]=1.f+c*(p1*p1-pp); V[5]=-b*p0+c*p1*p2;
        V[6]=-b*p1+c*p2*p0;     V[7]= b*p0+c*p2*p1;   V[8]=1.f+c*(p2*p2-pp);
        const float td0 = V[0]*r0 + V[1]*r1 + V[2]*r2;
        const float td1 = V[3]*r0 + V[4]*r1 + V[5]*r2;
        const float td2 = V[6]*r0 + V[7]*r1 + V[8]*r2;
        float TRn[9], Ttn[3];
#pragma unroll
        for (int q = 0; q < 9; q++) TRn[q] = T_R[9*n+q];
#pragma unroll
        for (int q = 0; q < 3; q++) Ttn[q] = T_t[3*n+q];
        float* o = out + (size_t)n * OUTC + 64;
#pragma unroll
        for (int r = 0; r < 3; r++)
#pragma unroll
            for (int cc = 0; cc < 3; cc++)
                o[3*r+cc] = Rd[3*r+0]*TRn[cc] + Rd[3*r+1]*TRn[3+cc] + Rd[3*r+2]*TRn[6+cc];
        o[9]  = Rd[0]*Ttn[0] + Rd[1]*Ttn[1] + Rd[2]*Ttn[2] + td0;
        o[10] = Rd[3]*Ttn[0] + Rd[4]*Ttn[1] + Rd[5]*Ttn[2] + td1;
        o[11] = Rd[6]*Ttn[0] + Rd[7]*Ttn[1] + Rd[8]*Ttn[2] + td2;
        o[12] = sqrtf(pp);
    }
}

extern "C" void kernel_launch(void* const* d_in, const int* in_sizes, int n_in,
                              void* d_out, int out_size, void* d_ws, size_t ws_size,
                              hipStream_t stream)
{
    const float* xfeat     = (const float*)d_in[0];
    const float* T_R       = (const float*)d_in[1];
    const float* T_t       = (const float*)d_in[2];
    const float* edge_feat = (const float*)d_in[3];
    const float* Tij_R     = (const float*)d_in[4];
    const float* Tij_t     = (const float*)d_in[5];
    const float* u         = (const float*)d_in[6];
    const int*   edge_index= (const int*)d_in[7];
    const int*   batch     = (const int*)d_in[8];
    const float* W1 = (const float*)d_in[9],  *b1 = (const float*)d_in[10];
    const float* W2 = (const float*)d_in[11], *b2 = (const float*)d_in[12];
    const float* W3 = (const float*)d_in[13], *b3 = (const float*)d_in[14];
    const float* W4 = (const float*)d_in[15], *b4 = (const float*)d_in[16];
    const int N = in_sizes[0] / ND;
    const int E = in_sizes[3] / ED;

    // ws: weights | xb | eb | poseb | hbuf | dinfo | cnti | off | cursor | btot
    char* p = (char*)d_ws;
    unsigned short* W1b = (unsigned short*)p;   p += (size_t)K1PAD * HD * 2;
    unsigned short* W2b = (unsigned short*)p;   p += (size_t)HD * HD * 2;
    unsigned short* W3b = (unsigned short*)p;   p += (size_t)KG * HD * 2;
    unsigned short* W4b = (unsigned short*)p;   p += (size_t)HD * N4P * 2;
    unsigned short* xb  = (unsigned short*)p;   p += (size_t)N * ND * 2;
    unsigned short* ebf = (unsigned short*)p;   p += (size_t)E * ED * 2;
    unsigned short* poseb = (unsigned short*)p; p += (size_t)2 * E * 16 * 2;
    unsigned short* hbuf = (unsigned short*)p;  p += (size_t)2 * E * HD * 2;
    int4* dinfo = (int4*)p;                     p += (size_t)2 * E * 16;
    int* cnti = (int*)p;                        p += (size_t)N * 4;
    int* off  = (int*)p;                        p += (size_t)N * 4;
    int* cursor = (int*)p;                      p += (size_t)N * 4;
    int* btot = (int*)p;

    hipMemsetAsync(cnti, 0, (size_t)N * 4, stream);
    const int prepn = K1PAD*HD + HD*HD + KG*HD + HD*N4P + N*ND/4 + E*ED/4 + 2*E;
    prep<<<(prepn + 255) / 256, 256, 0, stream>>>(W1, W2, W3, W4, xfeat, edge_feat,
                                                  edge_index, W1b, W2b, W3b, W4b,
                                                  xb, ebf, cnti, N, E);
    const int nsb = (N + SCB - 1) / SCB;
    scan1<<<nsb, 256, 0, stream>>>(cnti, off, btot, N);
    scan2<<<1, 64, 0, stream>>>(btot, nsb);
    scan3<<<(N + 255) / 256, 256, 0, stream>>>(off, btot, cursor, N);
    scatter_pose<<<(2*E + 255) / 256, 256, 0, stream>>>(T_R, T_t, Tij_R, Tij_t,
                                                        edge_index, cursor, dinfo, poseb, E);
    const int ebk = (2 * E + MT - 1) / MT;
    edge_kernel<<<ebk, 256, 0, stream>>>(xb, ebf, poseb, dinfo,
                                         W1b, b1, W2b, b2, hbuf, E);
    const int nb = (N + TDN - 1) / TDN;
    node_kernel<<<nb, 256, 0, stream>>>(xfeat, T_R, T_t, u, batch, W3b, b3, W4b, b4,
                                        hbuf, off, cnti, (float*)d_out, N);
}